// Round 1
// baseline (202.263 us; speedup 1.0000x reference)
//
#include <hip/hip_runtime.h>

#define SEQ 41
#define FEAT 128
#define KDIM 384
#define ROWLEN (SEQ * FEAT)        // 5248 floats per batch row
#define BM 128                     // rows per block = 4 waves x 32 rows

typedef float floatx4 __attribute__((ext_vector_type(4)));
typedef __bf16 bf16x8 __attribute__((ext_vector_type(8)));
typedef unsigned short ushortx8 __attribute__((ext_vector_type(8)));

// fp32 -> bf16 bits, round-to-nearest-even (prepass / fallback path)
__device__ __forceinline__ unsigned short f2bf(float f) {
    unsigned int u = __builtin_bit_cast(unsigned int, f);
    return (unsigned short)((u + 0x7fffu + ((u >> 16) & 1u)) >> 16);
}

// pack 8 fp32 (k = quad*8 + j; lo = j0..3, hi = j4..7) into one A/B fragment.
// native casts let the compiler emit v_cvt_pk_bf16_f32 (RTNE, same as f2bf).
__device__ __forceinline__ bf16x8 pack8(floatx4 lo, floatx4 hi) {
    bf16x8 r;
#pragma unroll
    for (int j = 0; j < 4; j++) { r[j] = (__bf16)lo[j]; r[4 + j] = (__bf16)hi[j]; }
    return r;
}

// ---------------- prepass: W[s][k][n] fp32 -> Wt2 in MFMA fragment order --------
// Wt2 linear layout: [s][slab(6)][ks(2)][nt(8)][lane(64)][8 bf16]
//   n = nt*16 + (lane&15);  k = slab*64 + ks*32 + (lane>>4)*8 + j
__global__ __launch_bounds__(256) void wt2_kernel(const float* __restrict__ W,
                                                  unsigned short* __restrict__ Wt2) {
    int t = blockIdx.x * 256 + threadIdx.x;   // exactly 41*6144 threads
    int s = t / 6144, g = t % 6144;
    int lane = g & 63, nt = (g >> 6) & 7, ks = (g >> 9) & 1, slab = g >> 10;
    int n  = nt * 16 + (lane & 15);
    int k0 = slab * 64 + ks * 32 + (lane >> 4) * 8;
    const float* Ws = W + (size_t)s * KDIM * FEAT;
    ushortx8 v;
#pragma unroll
    for (int j = 0; j < 8; j++) v[j] = f2bf(Ws[(size_t)(k0 + j) * FEAT + n]);
    *reinterpret_cast<ushortx8*>(Wt2 + (size_t)t * 8) = v;
}

// ---------------- main GEMM: LDS-free, barrier-free ----------------
// 4 independent waves / block; each wave owns a 32x128 output tile for one s.
// A frags loaded straight from X (8 contiguous fp32 per lane), B frags straight
// from fragment-ordered Wt2 (16 B per lane, L2-hot). A double-buffered in regs.
template <int USE_WT>
__global__ __launch_bounds__(256, 3) void gemm_kernel(const float* __restrict__ X,
                                                      const void* __restrict__ Wsrc,
                                                      const float* __restrict__ bias,
                                                      float* __restrict__ out) {
    const int tid  = threadIdx.x;
    const int lane = tid & 63;
    const int wv   = tid >> 6;
    const int s    = blockIdx.y;
    const int m0   = blockIdx.x * BM + wv * 32;

    // OOB window cols form whole 64-float slabs -> restrict K-range, no bounds checks
    const int klo = (s == 0) ? 2 : 0;
    const int khi = (s == SEQ - 1) ? 4 : 6;
    const int nst = (khi - klo) * 2;          // ks-steps of K=32; always even (8 or 12)

    const int colq = lane & 15, quad = lane >> 4;

    // A: lane holds row (lane&15) of its 16-row tile, k = quad*8 + j (8 contiguous fp32)
    // koff >= 0 for all s (s==0 has klo=2 cancelling obase=-128)
    const int koff = (s - 1) * FEAT + klo * 64 + quad * 8;
    const float* aptr0 = X + (size_t)(m0 + colq) * ROWLEN + koff;       // mt=0 rows
    const float* aptr1 = aptr0 + (size_t)16 * ROWLEN;                   // mt=1 rows

    const unsigned short* Wt2 = (const unsigned short*)Wsrc;
    const float* Wf = (const float*)Wsrc;
    // B frag (ks,nt): Wt2[(s*6+kki)*8192 + ks*4096 + nt*512 + lane*8]; linear in ksi (step 4096)
    const unsigned short* bptr = Wt2 + ((size_t)s * 6 + klo) * 8192 + lane * 8;

    floatx4 acc[2][8];
#pragma unroll
    for (int mi = 0; mi < 2; mi++)
#pragma unroll
        for (int ni = 0; ni < 8; ni++) acc[mi][ni] = (floatx4){0.f, 0.f, 0.f, 0.f};

    // register double-buffer for A (named buffers -> all indices static, no scratch)
    floatx4 aL0[2], aH0[2], aL1[2], aH1[2];

    auto loadA = [&](floatx4 (&L)[2], floatx4 (&H)[2], int ksi) {
        const float* p0 = aptr0 + ksi * 32;
        const float* p1 = aptr1 + ksi * 32;
        L[0] = *reinterpret_cast<const floatx4*>(p0);
        H[0] = *reinterpret_cast<const floatx4*>(p0 + 4);
        L[1] = *reinterpret_cast<const floatx4*>(p1);
        H[1] = *reinterpret_cast<const floatx4*>(p1 + 4);
    };

    auto step = [&](floatx4 (&L)[2], floatx4 (&H)[2], int ksi) {
        bf16x8 bfr[8];
        if (USE_WT) {
            const unsigned short* bp = bptr + (size_t)ksi * 4096;
#pragma unroll
            for (int ni = 0; ni < 8; ni++)
                bfr[ni] = *reinterpret_cast<const bf16x8*>(bp + ni * 512);
        } else {
            // fallback: gather from fp32 W[s][k][n] (uncoalesced, correctness path)
            int kk = klo * 64 + ksi * 32 + quad * 8;
#pragma unroll
            for (int ni = 0; ni < 8; ni++) {
                ushortx8 v;
#pragma unroll
                for (int j = 0; j < 8; j++)
                    v[j] = f2bf(Wf[((size_t)s * KDIM + kk + j) * FEAT + ni * 16 + colq]);
                bfr[ni] = __builtin_bit_cast(bf16x8, v);
            }
        }
        bf16x8 af0 = pack8(L[0], H[0]);
        bf16x8 af1 = pack8(L[1], H[1]);
        __builtin_amdgcn_s_setprio(1);
#pragma unroll
        for (int ni = 0; ni < 8; ni++) {
            acc[0][ni] = __builtin_amdgcn_mfma_f32_16x16x32_bf16(af0, bfr[ni], acc[0][ni], 0, 0, 0);
            acc[1][ni] = __builtin_amdgcn_mfma_f32_16x16x32_bf16(af1, bfr[ni], acc[1][ni], 0, 0, 0);
        }
        __builtin_amdgcn_s_setprio(0);
    };

    // software pipeline: A for step k+1 in flight while step k computes
    loadA(aL0, aH0, 0);
    for (int ksi = 0; ksi < nst; ksi += 2) {
        loadA(aL1, aH1, ksi + 1);              // nst even -> always valid
        step(aL0, aH0, ksi);
        if (ksi + 2 < nst) loadA(aL0, aH0, ksi + 2);
        step(aL1, aH1, ksi + 1);
    }

    // epilogue: bias + relu; C layout (verified): col = lane&15, row = quad*4 + r
#pragma unroll
    for (int ni = 0; ni < 8; ni++) {
        int n = ni * 16 + colq;
        float bv = bias[s * FEAT + n];
#pragma unroll
        for (int mi = 0; mi < 2; mi++) {
            size_t base = ((size_t)(m0 + mi * 16 + quad * 4) * SEQ + s) * FEAT + n;
#pragma unroll
            for (int r = 0; r < 4; r++) {
                float v = acc[mi][ni][r] + bv;
                v = v > 0.f ? v : 0.f;
                out[base + (size_t)r * (SEQ * FEAT)] = v;
            }
        }
    }
}

extern "C" void kernel_launch(void* const* d_in, const int* in_sizes, int n_in,
                              void* d_out, int out_size, void* d_ws, size_t ws_size,
                              hipStream_t stream) {
    const float* X    = (const float*)d_in[0];
    const float* W    = (const float*)d_in[1];
    const float* bias = (const float*)d_in[2];
    float* out = (float*)d_out;

    const int B = in_sizes[0] / ROWLEN;               // 4096
    dim3 grid(B / BM, SEQ);

    const size_t wt_bytes = (size_t)SEQ * 6 * 8192 * sizeof(unsigned short);  // ~4 MB
    if (ws_size >= wt_bytes) {
        unsigned short* Wt2 = (unsigned short*)d_ws;
        wt2_kernel<<<(SEQ * 6144) / 256, 256, 0, stream>>>(W, Wt2);
        gemm_kernel<1><<<grid, 256, 0, stream>>>(X, (const void*)Wt2, bias, out);
    } else {
        gemm_kernel<0><<<grid, 256, 0, stream>>>(X, (const void*)W, bias, out);
    }
}

// Round 2
// 192.145 us; speedup vs baseline: 1.0527x; 1.0527x over previous
//
#include <hip/hip_runtime.h>

#define SEQ 41
#define FEAT 128
#define KDIM 384
#define ROWLEN (SEQ * FEAT)        // 5248 floats per batch row
#define BM 256                     // rows per block = 8 waves x 32 rows

typedef float floatx4 __attribute__((ext_vector_type(4)));
typedef __bf16 bf16x8 __attribute__((ext_vector_type(8)));
typedef unsigned short ushortx8 __attribute__((ext_vector_type(8)));

// fp32 -> bf16 bits, round-to-nearest-even (prepass / fallback path)
__device__ __forceinline__ unsigned short f2bf(float f) {
    unsigned int u = __builtin_bit_cast(unsigned int, f);
    return (unsigned short)((u + 0x7fffu + ((u >> 16) & 1u)) >> 16);
}

// pack 8 fp32 (k = quad*8 + j) into one MFMA A-fragment (RTNE via native casts)
__device__ __forceinline__ bf16x8 pack8(floatx4 lo, floatx4 hi) {
    bf16x8 r;
#pragma unroll
    for (int j = 0; j < 4; j++) { r[j] = (__bf16)lo[j]; r[4 + j] = (__bf16)hi[j]; }
    return r;
}

// async global->LDS DMA, 16 B per lane; LDS dest = uniform base + lane*16,
// global src is per-lane.
#define DMA16(g, l)                                                          \
    __builtin_amdgcn_global_load_lds(                                        \
        (const __attribute__((address_space(1))) void*)(g),                  \
        (__attribute__((address_space(3))) void*)(l), 16, 0, 0)

// ---------------- prepass: W[s][k][n] fp32 -> Wt2 in MFMA fragment order --------
// Wt2 linear layout: [s][slab(6)][ks(2)][nt(8)][lane(64)][8 bf16]
//   n = nt*16 + (lane&15);  k = slab*64 + ks*32 + (lane>>4)*8 + j
__global__ __launch_bounds__(256) void wt2_kernel(const float* __restrict__ W,
                                                  unsigned short* __restrict__ Wt2) {
    int t = blockIdx.x * 256 + threadIdx.x;   // exactly 41*6144 threads
    int s = t / 6144, g = t % 6144;
    int lane = g & 63, nt = (g >> 6) & 7, ks = (g >> 9) & 1, slab = g >> 10;
    int n  = nt * 16 + (lane & 15);
    int k0 = slab * 64 + ks * 32 + (lane >> 4) * 8;
    const float* Ws = W + (size_t)s * KDIM * FEAT;
    ushortx8 v;
#pragma unroll
    for (int j = 0; j < 8; j++) v[j] = f2bf(Ws[(size_t)(k0 + j) * FEAT + n]);
    *reinterpret_cast<ushortx8*>(Wt2 + (size_t)t * 8) = v;
}

// ---------------- main GEMM ----------------
// 512 thr = 8 waves; each wave owns a 32x128 tile for one s.
// Stage ALL of B for this s into LDS once (64-96 KB, fragment order), ONE barrier,
// then a barrier-free K-loop: B via contiguous ds_read_b128, A register-prefetched
// 4 steps deep straight from X. Compiler emits counted vmcnt/lgkm waits (no drain).
template <int USE_WT>
__global__ __launch_bounds__(512, 2) void gemm_kernel(const float* __restrict__ X,
                                                      const void* __restrict__ Wsrc,
                                                      const float* __restrict__ bias,
                                                      float* __restrict__ out) {
    __shared__ unsigned short Bs[6 * 8192];   // 96 KB, [ksi(12)][nt(8)][lane(64)][8 bf16]

    const int tid  = threadIdx.x;
    const int lane = tid & 63;
    const int wv   = tid >> 6;
    const int s    = blockIdx.y;
    const int m0   = blockIdx.x * BM + wv * 32;

    // OOB window cols form whole 64-float slabs -> restrict K-range, no bounds checks
    const int klo = (s == 0) ? 2 : 0;
    const int khi = (s == SEQ - 1) ? 4 : 6;
    const int nk  = khi - klo;                // 4 or 6 K=64 slabs
    const int nst = nk * 2;                   // K=32 steps: 8 or 12 (multiple of 4)

    const int colq = lane & 15, quad = lane >> 4;

    // A: lane holds row (lane&15), k = quad*8 + j (8 contiguous fp32); koff >= 0 always
    const int koff = (s - 1) * FEAT + klo * 64 + quad * 8;
    const float* aptr0 = X + (size_t)(m0 + colq) * ROWLEN + koff;       // rows 0..15
    const float* aptr1 = aptr0 + (size_t)16 * ROWLEN;                   // rows 16..31

    floatx4 acc[2][8];
#pragma unroll
    for (int mi = 0; mi < 2; mi++)
#pragma unroll
        for (int ni = 0; ni < 8; ni++) acc[mi][ni] = (floatx4){0.f, 0.f, 0.f, 0.f};

    // 4-deep register A pipeline; struct members keep all indices static (no scratch)
    struct Abuf { floatx4 L0, H0, L1, H1; };
    Abuf A0, A1, A2, A3;

    auto loadA = [&](Abuf& ab, int ksi) {
        const float* p0 = aptr0 + ksi * 32;
        const float* p1 = aptr1 + ksi * 32;
        ab.L0 = *reinterpret_cast<const floatx4*>(p0);
        ab.H0 = *reinterpret_cast<const floatx4*>(p0 + 4);
        ab.L1 = *reinterpret_cast<const floatx4*>(p1);
        ab.H1 = *reinterpret_cast<const floatx4*>(p1 + 4);
    };

    auto step = [&](const Abuf& ab, int ksi) {
        bf16x8 bfr[8];
        const unsigned short* bp = &Bs[ksi * 4096 + lane * 8];
#pragma unroll
        for (int ni = 0; ni < 8; ni++)
            bfr[ni] = *reinterpret_cast<const bf16x8*>(bp + ni * 512);
        bf16x8 af0 = pack8(ab.L0, ab.H0);
        bf16x8 af1 = pack8(ab.L1, ab.H1);
        __builtin_amdgcn_s_setprio(1);
#pragma unroll
        for (int ni = 0; ni < 8; ni++) {
            acc[0][ni] = __builtin_amdgcn_mfma_f32_16x16x32_bf16(af0, bfr[ni], acc[0][ni], 0, 0, 0);
            acc[1][ni] = __builtin_amdgcn_mfma_f32_16x16x32_bf16(af1, bfr[ni], acc[1][ni], 0, 0, 0);
        }
        __builtin_amdgcn_s_setprio(0);
    };

    // ---- prologue: A pipeline fill + whole-K B staging, single barrier ----
    loadA(A0, 0); loadA(A1, 1); loadA(A2, 2); loadA(A3, 3);

    if (USE_WT) {
        const unsigned short* wsrc =
            (const unsigned short*)Wsrc + ((size_t)s * 6 + klo) * 8192;
        const int nwi = nk * 16;              // 1 KB wave-instructions total
        for (int i = wv; i < nwi; i += 8)
            DMA16(wsrc + (size_t)i * 512 + lane * 8, &Bs[(size_t)i * 512]);
    } else {
        // fallback: gather from fp32 W[s][k][n] into fragment order (correctness path)
        const float* Wf = (const float*)Wsrc;
        for (int j = tid; j < nk * 1024; j += 512) {
            int ln = j & 63, nt = (j >> 6) & 7, ksa = j >> 9;
            int k = klo * 64 + ksa * 32 + (ln >> 4) * 8;
            int n = nt * 16 + (ln & 15);
            ushortx8 v;
#pragma unroll
            for (int jj = 0; jj < 8; jj++)
                v[jj] = f2bf(Wf[((size_t)s * KDIM + k + jj) * FEAT + n]);
            *reinterpret_cast<ushortx8*>(&Bs[(size_t)j * 8]) = v;
        }
    }
    __syncthreads();                          // the ONLY barrier

    // ---- barrier-free K-loop, A prefetched 4 steps ahead ----
    int ksi = 0;
    for (; ksi + 4 < nst; ksi += 4) {
        step(A0, ksi + 0); loadA(A0, ksi + 4);
        step(A1, ksi + 1); loadA(A1, ksi + 5);
        step(A2, ksi + 2); loadA(A2, ksi + 6);
        step(A3, ksi + 3); loadA(A3, ksi + 7);
    }
    step(A0, ksi + 0); step(A1, ksi + 1); step(A2, ksi + 2); step(A3, ksi + 3);

    // ---- epilogue: bias + relu; C layout: col = lane&15, row = quad*4 + r ----
#pragma unroll
    for (int ni = 0; ni < 8; ni++) {
        int n = ni * 16 + colq;
        float bv = bias[s * FEAT + n];
#pragma unroll
        for (int mi = 0; mi < 2; mi++) {
            size_t base = ((size_t)(m0 + mi * 16 + quad * 4) * SEQ + s) * FEAT + n;
#pragma unroll
            for (int r = 0; r < 4; r++) {
                float v = acc[mi][ni][r] + bv;
                v = v > 0.f ? v : 0.f;
                out[base + (size_t)r * (SEQ * FEAT)] = v;
            }
        }
    }
}

extern "C" void kernel_launch(void* const* d_in, const int* in_sizes, int n_in,
                              void* d_out, int out_size, void* d_ws, size_t ws_size,
                              hipStream_t stream) {
    const float* X    = (const float*)d_in[0];
    const float* W    = (const float*)d_in[1];
    const float* bias = (const float*)d_in[2];
    float* out = (float*)d_out;

    const int B = in_sizes[0] / ROWLEN;               // 4096
    dim3 grid(B / BM, SEQ);

    const size_t wt_bytes = (size_t)SEQ * 6 * 8192 * sizeof(unsigned short);  // ~4 MB
    if (ws_size >= wt_bytes) {
        unsigned short* Wt2 = (unsigned short*)d_ws;
        wt2_kernel<<<(SEQ * 6144) / 256, 256, 0, stream>>>(W, Wt2);
        gemm_kernel<1><<<grid, 512, 0, stream>>>(X, (const void*)Wt2, bias, out);
    } else {
        gemm_kernel<0><<<grid, 512, 0, stream>>>(X, (const void*)W, bias, out);
    }
}